// Round 4
// baseline (512.535 us; speedup 1.0000x reference)
//
#include <hip/hip_runtime.h>
#include <hip/hip_bf16.h>
#include <cstddef>
#include <cstdint>

namespace {
constexpr int Bn = 4, SEQ = 2048, CDIM = 1024, NH = 16, DH = 64;
constexpr int Mrows = Bn * SEQ;  // 8192
}

using bf16x8 = __attribute__((ext_vector_type(8))) __bf16;
using f32x4  = __attribute__((ext_vector_type(4))) float;

#define MFMA16(a, b, c) __builtin_amdgcn_mfma_f32_16x16x32_bf16(a, b, c, 0, 0, 0)

__device__ __forceinline__ void gload_lds16(const __bf16* g, __bf16* l) {
  __builtin_amdgcn_global_load_lds(
      (const __attribute__((address_space(1))) void*)g,
      (__attribute__((address_space(3))) void*)l, 16, 0, 0);
}

__device__ __forceinline__ unsigned pk2(float a, float b) {
  union { __bf16 h[2]; unsigned u; } x;
  x.h[0] = (__bf16)a; x.h[1] = (__bf16)b;
  return x.u;
}

// ---------------------------------------------------------------------------
// Cast x and the 4 weight matrices to bf16.  wall rows: [Wq;Wk;Wv;Wo].
// ---------------------------------------------------------------------------
__global__ __launch_bounds__(256) void cast_inputs(
    const float* __restrict__ x, const float* __restrict__ wq,
    const float* __restrict__ wk, const float* __restrict__ wv,
    const float* __restrict__ wo, __bf16* __restrict__ xb,
    __bf16* __restrict__ wall) {
  constexpr int X4 = Mrows * CDIM / 4;  // 2M float4
  constexpr int W4 = CDIM * CDIM / 4;   // 256K float4 (== 1<<18)
  constexpr int total = X4 + 4 * W4;
  for (int i = blockIdx.x * 256 + threadIdx.x; i < total; i += gridDim.x * 256) {
    const float4* src;
    __bf16* dst;
    int o;
    if (i < X4) {
      src = (const float4*)x; dst = xb; o = i;
    } else {
      int j = i - X4;
      int w = j >> 18;
      o = j & (W4 - 1);
      src = (const float4*)(w == 0 ? wq : w == 1 ? wk : w == 2 ? wv : wo);
      dst = wall + (size_t)w * (CDIM * CDIM);
    }
    float4 v = src[o];
    union { __bf16 h[4]; ushort4 u4; } pk;
    pk.h[0] = (__bf16)v.x; pk.h[1] = (__bf16)v.y;
    pk.h[2] = (__bf16)v.z; pk.h[3] = (__bf16)v.w;
    *(ushort4*)(dst + (size_t)o * 4) = pk.u4;
  }
}

// ---------------------------------------------------------------------------
// bf16 MFMA GEMM, m97 structure: 128x128 tile, BK=32, 4 waves (2x2), each wave
// 64x64 = 4x4 fragments of 16x16x32.  (unchanged from round 3 — verified)
// ---------------------------------------------------------------------------
template <int MODE>
__global__ __launch_bounds__(256) void gemm_mfma(
    const __bf16* __restrict__ A, const __bf16* __restrict__ Bw,
    const float* __restrict__ b0, const float* __restrict__ b1,
    const float* __restrict__ b2, __bf16* __restrict__ Qb,
    __bf16* __restrict__ Kb, __bf16* __restrict__ Vb,
    float* __restrict__ Yf) {
  __shared__ __align__(16) __bf16 As[128 * 32];
  __shared__ __align__(16) __bf16 Bs[128 * 32];
  const int tid = threadIdx.x;
  const int lane = tid & 63, w = tid >> 6;
  const int wr = w >> 1, wc = w & 1;
  const int l4 = lane >> 4, l15 = lane & 15;
  const int m0 = blockIdx.y * 128, n0 = blockIdx.x * 128;

  f32x4 acc[4][4] = {};
  const int srow = lane >> 2;
  const int scol = (lane & 3) * 8;

  for (int k0 = 0; k0 < CDIM; k0 += 32) {
    __syncthreads();
#pragma unroll
    for (int u = 0; u < 2; ++u) {
      const int c = w * 2 + u;
      gload_lds16(A + (size_t)(m0 + c * 16 + srow) * CDIM + k0 + scol,
                  &As[c * 512]);
      gload_lds16(Bw + (size_t)(n0 + c * 16 + srow) * CDIM + k0 + scol,
                  &Bs[c * 512]);
    }
    __syncthreads();
    bf16x8 af[4], bfr[4];
#pragma unroll
    for (int i = 0; i < 4; ++i)
      af[i] = *(const bf16x8*)&As[(wr * 64 + i * 16 + l15) * 32 + l4 * 8];
#pragma unroll
    for (int j = 0; j < 4; ++j)
      bfr[j] = *(const bf16x8*)&Bs[(wc * 64 + j * 16 + l15) * 32 + l4 * 8];
#pragma unroll
    for (int i = 0; i < 4; ++i)
#pragma unroll
      for (int j = 0; j < 4; ++j)
        acc[i][j] = MFMA16(af[i], bfr[j], acc[i][j]);
  }

  const int row0 = m0 + wr * 64;
  if (MODE == 0) {
#pragma unroll
    for (int j = 0; j < 4; ++j) {
      const int n = (n0 + wc * 64 + j * 16) + l15;
      const float bias = b0[n];
#pragma unroll
      for (int i = 0; i < 4; ++i) {
        const int mrow = row0 + i * 16 + l4 * 4;
#pragma unroll
        for (int r = 0; r < 4; ++r)
          Yf[(size_t)(mrow + r) * CDIM + n] = acc[i][j][r] + bias;
      }
    }
  } else {
    const int which = n0 >> 10;
    const float* bias = which == 0 ? b0 : which == 1 ? b1 : b2;
    __bf16* Out = which == 0 ? Qb : which == 1 ? Kb : Vb;
    const float scl = which == 0 ? 0.125f : 1.0f;
    const int n0c = n0 & 1023;
#pragma unroll
    for (int j = 0; j < 4; ++j) {
      const int c = n0c + wc * 64 + j * 16 + l15;
      const int h = c >> 6, dh = c & 63;
      const float bias_v = bias[c];
#pragma unroll
      for (int i = 0; i < 4; ++i) {
        const int mrow = row0 + i * 16 + l4 * 4;
#pragma unroll
        for (int r = 0; r < 4; ++r) {
          const int m = mrow + r;
          const int b_ = m >> 11, ns = m & (SEQ - 1);
          Out[((size_t)(b_ * NH + h) * SEQ + ns) * DH + dh] =
              (__bf16)((acc[i][j][r] + bias_v) * scl);
        }
      }
    }
  }
}

// ---------------------------------------------------------------------------
// Flash attention v2: SWAPPED QK^T (mfma(K,Q)) so each lane owns one q-row
// (q = l15) and 16 key-values in registers.  Softmax: in-register + 2 shfls.
// P: packed to bf16 in-register, redistributed to the PV B-fragment layout
// with 16 shfls (no LDS).  PV: O^T = mfma(V^T-frag, P^T-frag).  vT only LDS.
// ---------------------------------------------------------------------------
__global__ __launch_bounds__(256) void attn_mfma(
    const __bf16* __restrict__ Qg, const __bf16* __restrict__ Kg,
    const __bf16* __restrict__ Vg, __bf16* __restrict__ AO) {
  __shared__ __align__(16) __bf16 vT[DH][80];  // [d][key], 160B rows (16B-mult)
  const int tid = threadIdx.x, lane = tid & 63, w = tid >> 6;
  const int l4 = lane >> 4, l15 = lane & 15;
  const int bh = blockIdx.x, qt = blockIdx.y;
  const int b_ = bh >> 4, h_ = bh & 15;

  const __bf16* Qb = Qg + ((size_t)bh * SEQ + qt * 64 + w * 16) * DH;
  const __bf16* Kb = Kg + (size_t)bh * SEQ * DH;
  const __bf16* Vb = Vg + (size_t)bh * SEQ * DH;

  // Q as B-operand: lane holds Q[q=l15][d = t*32 + l4*8 .. +8]  (pre-scaled)
  bf16x8 q[2];
#pragma unroll
  for (int t = 0; t < 2; ++t)
    q[t] = *(const bf16x8*)(Qb + (size_t)l15 * DH + t * 32 + l4 * 8);

  f32x4 o[4] = {};           // O^T: lane holds O[d=fd*16+l4*4+r][q=l15]
  float m_i = -1e30f, l_i = 0.f;

  const int vkey = tid & 63;        // V staging: key this thread copies
  const int vdg = (tid >> 6) * 16;  // its 16-d slab

  for (int kt = 0; kt < SEQ / 64; ++kt) {
    const __bf16* Kt = Kb + (size_t)kt * 64 * DH;
    const __bf16* Vt = Vb + (size_t)kt * 64 * DH;
    __syncthreads();  // previous PV readers done with vT
    // V tile -> regs early (latency hides under QK^T)
    bf16x8 vr0 = *(const bf16x8*)(Vt + (size_t)vkey * DH + vdg);
    bf16x8 vr1 = *(const bf16x8*)(Vt + (size_t)vkey * DH + vdg + 8);
    // Swapped QK^T: A=K-frag, B=Q-frag -> S^T: lane holds
    // s[f][r] = S[key=f*16+l4*4+r][q=l15]
    f32x4 s[4];
#pragma unroll
    for (int f = 0; f < 4; ++f) {
      bf16x8 k0 = *(const bf16x8*)(Kt + (size_t)(f * 16 + l15) * DH + l4 * 8);
      bf16x8 k1 = *(const bf16x8*)(Kt + (size_t)(f * 16 + l15) * DH + 32 + l4 * 8);
      f32x4 z = {};
      z = MFMA16(k0, q[0], z);
      s[f] = MFMA16(k1, q[1], z);
    }
    // stage vT (contiguous 128B row-writes: conflict-free)
#pragma unroll
    for (int e = 0; e < 8; ++e) vT[vdg + e][vkey] = vr0[e];
#pragma unroll
    for (int e = 0; e < 8; ++e) vT[vdg + 8 + e][vkey] = vr1[e];

    // ---- online softmax: lane owns the full (half-)row of q=l15 ----
    float mx = s[0][0];
#pragma unroll
    for (int f = 0; f < 4; ++f)
#pragma unroll
      for (int r = 0; r < 4; ++r) mx = fmaxf(mx, s[f][r]);
    mx = fmaxf(mx, __shfl_xor(mx, 16));
    mx = fmaxf(mx, __shfl_xor(mx, 32));
    // defer-max (exact when skipped: alpha would be 1 only if m_i>=mx; here we
    // keep the old offset, p bounded by e^8 -- fine in bf16/f32)
    if (!__all(mx <= m_i + 8.0f)) {
      const float mnew = fmaxf(m_i, mx);
      const float alpha = __expf(m_i - mnew);
      m_i = mnew;
      l_i *= alpha;
#pragma unroll
      for (int fd = 0; fd < 4; ++fd) o[fd] *= alpha;
    }
    float ps = 0.f;
    unsigned w8[4][2];  // [f][j]: keys (f*16+l4*4+2j, +1) of q=l15, bf16x2
#pragma unroll
    for (int f = 0; f < 4; ++f) {
      float p0 = __expf(s[f][0] - m_i);
      float p1 = __expf(s[f][1] - m_i);
      float p2 = __expf(s[f][2] - m_i);
      float p3 = __expf(s[f][3] - m_i);
      ps += (p0 + p1) + (p2 + p3);
      w8[f][0] = pk2(p0, p1);
      w8[f][1] = pk2(p2, p3);
    }
    ps += __shfl_xor(ps, 16);
    ps += __shfl_xor(ps, 32);
    l_i += ps;

    // ---- redistribute P to PV B-frag layout (derivation in header) ----
    // dest word (t,j2) covers keys t*32+l4*8+2*j2,+1 for q=l15; source is
    // word w8[2t+(l4>>1)][j2&1] of lane ((l4&1)*2+(j2>>1))*16 + l15.
    const int srcbase = (l4 & 1) * 32 + l15;
    unsigned pbw[2][4];
#pragma unroll
    for (int t = 0; t < 2; ++t) {
#pragma unroll
      for (int j2 = 0; j2 < 4; ++j2) {
        const int src = srcbase + (j2 >> 1) * 16;
        const unsigned lo = __shfl(w8[2 * t][j2 & 1], src);
        const unsigned hi = __shfl(w8[2 * t + 1][j2 & 1], src);
        pbw[t][j2] = (l4 & 2) ? hi : lo;
      }
    }
    __syncthreads();  // vT ready for all waves

    // ---- PV: O^T += V^T-frag x P^T-frag ----
    union { unsigned u[4]; bf16x8 v; } pb0, pb1;
#pragma unroll
    for (int j2 = 0; j2 < 4; ++j2) { pb0.u[j2] = pbw[0][j2]; pb1.u[j2] = pbw[1][j2]; }
#pragma unroll
    for (int fd = 0; fd < 4; ++fd) {
      bf16x8 va = *(const bf16x8*)&vT[fd * 16 + l15][l4 * 8];
      bf16x8 vb = *(const bf16x8*)&vT[fd * 16 + l15][32 + l4 * 8];
      o[fd] = MFMA16(va, pb0.v, o[fd]);
      o[fd] = MFMA16(vb, pb1.v, o[fd]);
    }
  }

  // epilogue: lane holds O[d=fd*16+l4*4+r][q=l15]; normalize, pack pairs,
  // store u32 to AO[b, q, h*64 + d]
  const float inv = 1.f / l_i;
  const int qglob = qt * 64 + w * 16 + l15;
  __bf16* aorow = AO + ((size_t)(b_ * SEQ) + qglob) * CDIM + h_ * DH;
#pragma unroll
  for (int fd = 0; fd < 4; ++fd) {
    const int col = fd * 16 + l4 * 4;
    *(unsigned*)(aorow + col) = pk2(o[fd][0] * inv, o[fd][1] * inv);
    *(unsigned*)(aorow + col + 2) = pk2(o[fd][2] * inv, o[fd][3] * inv);
  }
}

// ---------------------------------------------------------------------------
extern "C" void kernel_launch(void* const* d_in, const int* in_sizes, int n_in,
                              void* d_out, int out_size, void* d_ws,
                              size_t ws_size, hipStream_t stream) {
  const float* x  = (const float*)d_in[0];
  const float* Wq = (const float*)d_in[1];
  const float* bq = (const float*)d_in[2];
  const float* Wk = (const float*)d_in[3];
  const float* bk = (const float*)d_in[4];
  const float* Wv = (const float*)d_in[5];
  const float* bv = (const float*)d_in[6];
  const float* Wo = (const float*)d_in[7];
  const float* bo = (const float*)d_in[8];
  float* out = (float*)d_out;

  __bf16* xb   = (__bf16*)d_ws;
  __bf16* wall = xb + (size_t)Mrows * CDIM;
  __bf16* Qb   = wall + (size_t)4 * CDIM * CDIM;
  __bf16* Kb   = Qb + (size_t)Mrows * CDIM;
  __bf16* Vb   = Kb + (size_t)Mrows * CDIM;
  __bf16* AO   = Vb + (size_t)Mrows * CDIM;

  cast_inputs<<<2048, 256, 0, stream>>>(x, Wq, Wk, Wv, Wo, xb, wall);
  gemm_mfma<1><<<dim3(24, 64), 256, 0, stream>>>(xb, wall, bq, bk, bv, Qb, Kb,
                                                 Vb, nullptr);
  attn_mfma<<<dim3(Bn * NH, SEQ / 64), 256, 0, stream>>>(Qb, Kb, Vb, AO);
  gemm_mfma<0><<<dim3(8, 64), 256, 0, stream>>>(
      AO, wall + (size_t)3 * CDIM * CDIM, bo, nullptr, nullptr, nullptr,
      nullptr, nullptr, out);
}

// Round 5
// 344.450 us; speedup vs baseline: 1.4880x; 1.4880x over previous
//
#include <hip/hip_runtime.h>
#include <hip/hip_bf16.h>
#include <cstddef>
#include <cstdint>

namespace {
constexpr int Bn = 4, SEQ = 2048, CDIM = 1024, NH = 16, DH = 64;
constexpr int Mrows = Bn * SEQ;  // 8192
}

using bf16x8 = __attribute__((ext_vector_type(8))) __bf16;
using f32x4  = __attribute__((ext_vector_type(4))) float;
using f32x16 = __attribute__((ext_vector_type(16))) float;

#define MFMA16(a, b, c) __builtin_amdgcn_mfma_f32_16x16x32_bf16(a, b, c, 0, 0, 0)
#define MFMA32(a, b, c) __builtin_amdgcn_mfma_f32_32x32x16_bf16(a, b, c, 0, 0, 0)

__device__ __forceinline__ void gload_lds16(const __bf16* g, __bf16* l) {
  __builtin_amdgcn_global_load_lds(
      (const __attribute__((address_space(1))) void*)g,
      (__attribute__((address_space(3))) void*)l, 16, 0, 0);
}

__device__ __forceinline__ unsigned pk2(float a, float b) {
  union { __bf16 h[2]; unsigned u; } x;
  x.h[0] = (__bf16)a; x.h[1] = (__bf16)b;
  return x.u;
}

// ---------------------------------------------------------------------------
// Cast x and the 4 weight matrices to bf16.  wall rows: [Wq;Wk;Wv;Wo].
// ---------------------------------------------------------------------------
__global__ __launch_bounds__(256) void cast_inputs(
    const float* __restrict__ x, const float* __restrict__ wq,
    const float* __restrict__ wk, const float* __restrict__ wv,
    const float* __restrict__ wo, __bf16* __restrict__ xb,
    __bf16* __restrict__ wall) {
  constexpr int X4 = Mrows * CDIM / 4;  // 2M float4
  constexpr int W4 = CDIM * CDIM / 4;   // 256K float4 (== 1<<18)
  constexpr int total = X4 + 4 * W4;
  for (int i = blockIdx.x * 256 + threadIdx.x; i < total; i += gridDim.x * 256) {
    const float4* src;
    __bf16* dst;
    int o;
    if (i < X4) {
      src = (const float4*)x; dst = xb; o = i;
    } else {
      int j = i - X4;
      int w = j >> 18;
      o = j & (W4 - 1);
      src = (const float4*)(w == 0 ? wq : w == 1 ? wk : w == 2 ? wv : wo);
      dst = wall + (size_t)w * (CDIM * CDIM);
    }
    float4 v = src[o];
    union { __bf16 h[4]; ushort4 u4; } pk;
    pk.h[0] = (__bf16)v.x; pk.h[1] = (__bf16)v.y;
    pk.h[2] = (__bf16)v.z; pk.h[3] = (__bf16)v.w;
    *(ushort4*)(dst + (size_t)o * 4) = pk.u4;
  }
}

// ---------------------------------------------------------------------------
// bf16 MFMA GEMM (unchanged from round 3 — verified).
// ---------------------------------------------------------------------------
template <int MODE>
__global__ __launch_bounds__(256) void gemm_mfma(
    const __bf16* __restrict__ A, const __bf16* __restrict__ Bw,
    const float* __restrict__ b0, const float* __restrict__ b1,
    const float* __restrict__ b2, __bf16* __restrict__ Qb,
    __bf16* __restrict__ Kb, __bf16* __restrict__ Vb,
    float* __restrict__ Yf) {
  __shared__ __align__(16) __bf16 As[128 * 32];
  __shared__ __align__(16) __bf16 Bs[128 * 32];
  const int tid = threadIdx.x;
  const int lane = tid & 63, w = tid >> 6;
  const int wr = w >> 1, wc = w & 1;
  const int l4 = lane >> 4, l15 = lane & 15;
  const int m0 = blockIdx.y * 128, n0 = blockIdx.x * 128;

  f32x4 acc[4][4] = {};
  const int srow = lane >> 2;
  const int scol = (lane & 3) * 8;

  for (int k0 = 0; k0 < CDIM; k0 += 32) {
    __syncthreads();
#pragma unroll
    for (int u = 0; u < 2; ++u) {
      const int c = w * 2 + u;
      gload_lds16(A + (size_t)(m0 + c * 16 + srow) * CDIM + k0 + scol,
                  &As[c * 512]);
      gload_lds16(Bw + (size_t)(n0 + c * 16 + srow) * CDIM + k0 + scol,
                  &Bs[c * 512]);
    }
    __syncthreads();
    bf16x8 af[4], bfr[4];
#pragma unroll
    for (int i = 0; i < 4; ++i)
      af[i] = *(const bf16x8*)&As[(wr * 64 + i * 16 + l15) * 32 + l4 * 8];
#pragma unroll
    for (int j = 0; j < 4; ++j)
      bfr[j] = *(const bf16x8*)&Bs[(wc * 64 + j * 16 + l15) * 32 + l4 * 8];
#pragma unroll
    for (int i = 0; i < 4; ++i)
#pragma unroll
      for (int j = 0; j < 4; ++j)
        acc[i][j] = MFMA16(af[i], bfr[j], acc[i][j]);
  }

  const int row0 = m0 + wr * 64;
  if (MODE == 0) {
#pragma unroll
    for (int j = 0; j < 4; ++j) {
      const int n = (n0 + wc * 64 + j * 16) + l15;
      const float bias = b0[n];
#pragma unroll
      for (int i = 0; i < 4; ++i) {
        const int mrow = row0 + i * 16 + l4 * 4;
#pragma unroll
        for (int r = 0; r < 4; ++r)
          Yf[(size_t)(mrow + r) * CDIM + n] = acc[i][j][r] + bias;
      }
    }
  } else {
    const int which = n0 >> 10;
    const float* bias = which == 0 ? b0 : which == 1 ? b1 : b2;
    __bf16* Out = which == 0 ? Qb : which == 1 ? Kb : Vb;
    const float scl = which == 0 ? 0.125f : 1.0f;
    const int n0c = n0 & 1023;
#pragma unroll
    for (int j = 0; j < 4; ++j) {
      const int c = n0c + wc * 64 + j * 16 + l15;
      const int h = c >> 6, dh = c & 63;
      const float bias_v = bias[c];
#pragma unroll
      for (int i = 0; i < 4; ++i) {
        const int mrow = row0 + i * 16 + l4 * 4;
#pragma unroll
        for (int r = 0; r < 4; ++r) {
          const int m = mrow + r;
          const int b_ = m >> 11, ns = m & (SEQ - 1);
          Out[((size_t)(b_ * NH + h) * SEQ + ns) * DH + dh] =
              (__bf16)((acc[i][j][r] + bias_v) * scl);
        }
      }
    }
  }
}

// ---------------------------------------------------------------------------
// Flash attention v3: 32x32x16 MFMA, 32 q-rows/wave, K prefetched one tile
// ahead (registers), V double-buffered in LDS (one barrier per tile),
// in-register softmax (1 shfl per reduce), P exchanged via 8 shfl_xor(32).
//
// S^T = mfma(A=K-frag, B=Q-frag): lane owns q-col = l31; S rows (keys) at
// (reg&3)+8*(reg>>2)+4*hi  [m101-verified 32x32 C/D layout].
// O^T = mfma(A=V^T-frag, B=P^T-frag) accumulated per d-tile.
// ---------------------------------------------------------------------------
__global__ __launch_bounds__(256) void attn_mfma(
    const __bf16* __restrict__ Qg, const __bf16* __restrict__ Kg,
    const __bf16* __restrict__ Vg, __bf16* __restrict__ AO) {
  __shared__ __align__(16) __bf16 vT[2][64][72];  // [buf][d][key], 144B rows
  const int tid = threadIdx.x, lane = tid & 63, w = tid >> 6;
  const int l31 = lane & 31, hi = lane >> 5;
  const int bh = blockIdx.x, qt = blockIdx.y;
  const int b_ = bh >> 4, h_ = bh & 15;

  const __bf16* Qp = Qg + ((size_t)bh * SEQ + qt * 128 + w * 32) * DH;
  const __bf16* Kb = Kg + (size_t)bh * SEQ * DH;
  const __bf16* Vb = Vg + (size_t)bh * SEQ * DH;

  // Q B-frags: lane holds Q[q=l31][d = t*16 + hi*8 + e]  (pre-scaled)
  bf16x8 q[4];
#pragma unroll
  for (int t = 0; t < 4; ++t)
    q[t] = *(const bf16x8*)(Qp + (size_t)l31 * DH + t * 16 + hi * 8);

  f32x16 o0 = {}, o1 = {};  // O^T: lane q=l31, d = X*32 + (j&3)+8*(j>>2)+4*hi
  float m_i = -1e30f, l_i = 0.f;

  const int vkey = tid & 63, vdg = (tid >> 6) * 16;  // V staging slice

  bf16x8 kfA[8], kfB[8];  // K A-frags: [c*4+t]: K[key=c*32+l31][d=t*16+hi*8+e]
  auto kload = [&](bf16x8(&kf)[8], int kt) {
#pragma unroll
    for (int c = 0; c < 2; ++c)
#pragma unroll
      for (int t = 0; t < 4; ++t)
        kf[c * 4 + t] = *(const bf16x8*)(
            Kb + ((size_t)kt * 64 + c * 32 + l31) * DH + t * 16 + hi * 8);
  };
  kload(kfA, 0);

  auto body = [&](bf16x8(&kc)[8], bf16x8(&kn)[8], int kt, int buf) {
    const __bf16* Vt = Vb + (size_t)kt * 64 * DH;
    // V tile -> regs (consumed by LDS write after QK^T; latency hidden)
    bf16x8 vr0 = *(const bf16x8*)(Vt + (size_t)vkey * DH + vdg);
    bf16x8 vr1 = *(const bf16x8*)(Vt + (size_t)vkey * DH + vdg + 8);
    // QK^T from prefetched K (no load on critical path)
    f32x16 s0 = {}, s1 = {};
#pragma unroll
    for (int t = 0; t < 4; ++t) {
      s0 = MFMA32(kc[t], q[t], s0);
      s1 = MFMA32(kc[4 + t], q[t], s1);
    }
    // prefetch next K tile (consumed next iteration)
    kload(kn, (kt + 1) & 31);
    // stage V^T (each thread owns disjoint cells; contiguous 128B per instr)
#pragma unroll
    for (int e = 0; e < 8; ++e) vT[buf][vdg + e][vkey] = vr0[e];
#pragma unroll
    for (int e = 0; e < 8; ++e) vT[buf][vdg + 8 + e][vkey] = vr1[e];
    // ---- softmax: lane owns 32 of 64 keys for its q; partner = lane^32 ----
    float mx = s0[0];
#pragma unroll
    for (int j = 1; j < 16; ++j) mx = fmaxf(mx, s0[j]);
#pragma unroll
    for (int j = 0; j < 16; ++j) mx = fmaxf(mx, s1[j]);
    mx = fmaxf(mx, __shfl_xor(mx, 32));
    if (!__all(mx <= m_i + 8.0f)) {  // defer-max (exact)
      const float mnew = fmaxf(m_i, mx);
      const float alpha = __expf(m_i - mnew);
      m_i = mnew;
      l_i *= alpha;
      o0 *= alpha;
      o1 *= alpha;
    }
    // exp + pack:  W[X][m][j2] = bf16x2 of keys (X*32 + 8m+4hi+2j2, +1)
    unsigned W0[4][2], W1[4][2];
    float ps = 0.f;
#pragma unroll
    for (int m = 0; m < 4; ++m)
#pragma unroll
      for (int j2 = 0; j2 < 2; ++j2) {
        float a0 = __expf(s0[4 * m + 2 * j2] - m_i);
        float a1 = __expf(s0[4 * m + 2 * j2 + 1] - m_i);
        float b0 = __expf(s1[4 * m + 2 * j2] - m_i);
        float b1 = __expf(s1[4 * m + 2 * j2 + 1] - m_i);
        ps += (a0 + a1) + (b0 + b1);
        W0[m][j2] = pk2(a0, a1);
        W1[m][j2] = pk2(b0, b1);
      }
    ps += __shfl_xor(ps, 32);
    l_i += ps;
    // ---- exchange -> P^T B-frags Bp[ks]: k=key=ks*16+hi*8+e, col q=l31 ----
    // own half uses m = 2*ks2 + hi; partner's same-index word fills the other
    // half via shfl_xor(32) of the selected send word (verified lane-by-lane).
    bf16x8 Bp[4];
#pragma unroll
    for (int X = 0; X < 2; ++X)
#pragma unroll
      for (int k2 = 0; k2 < 2; ++k2) {
        union { unsigned u[4]; bf16x8 v; } bb;
#pragma unroll
        for (int j2 = 0; j2 < 2; ++j2) {
          const unsigned a = X ? W1[2 * k2][j2] : W0[2 * k2][j2];
          const unsigned b = X ? W1[2 * k2 + 1][j2] : W0[2 * k2 + 1][j2];
          const unsigned snd = hi ? a : b;
          const unsigned rcv = __shfl_xor(snd, 32);
          bb.u[j2] = hi ? rcv : a;
          bb.u[2 + j2] = hi ? b : rcv;
        }
        Bp[X * 2 + k2] = bb.v;
      }
    __syncthreads();  // vT[buf] fully staged
    // ---- PV: O^T += V^T-frag x P^T-frag ----
#pragma unroll
    for (int ks = 0; ks < 4; ++ks) {
      bf16x8 va0 = *(const bf16x8*)&vT[buf][l31][ks * 16 + hi * 8];
      bf16x8 va1 = *(const bf16x8*)&vT[buf][32 + l31][ks * 16 + hi * 8];
      o0 = MFMA32(va0, Bp[ks], o0);
      o1 = MFMA32(va1, Bp[ks], o1);
    }
  };

#pragma unroll 1
  for (int kt2 = 0; kt2 < 16; ++kt2) {
    body(kfA, kfB, 2 * kt2, 0);
    body(kfB, kfA, 2 * kt2 + 1, 1);
  }

  // epilogue: lane q=l31; d = X*32 + 8*(u>>1) + 4*hi + 2*(u&1) for reg pair
  // (2u, 2u+1); pack pairs, u32 stores to AO[b, q, h*64 + d].
  const float inv = 1.f / l_i;
  const int qglob = qt * 128 + w * 32 + l31;
  __bf16* aorow = AO + ((size_t)(b_ * SEQ) + qglob) * CDIM + h_ * DH;
#pragma unroll
  for (int u = 0; u < 8; ++u) {
    const int dbase = 8 * (u >> 1) + 4 * hi + 2 * (u & 1);
    *(unsigned*)(aorow + dbase) = pk2(o0[2 * u] * inv, o0[2 * u + 1] * inv);
    *(unsigned*)(aorow + 32 + dbase) = pk2(o1[2 * u] * inv, o1[2 * u + 1] * inv);
  }
}

// ---------------------------------------------------------------------------
extern "C" void kernel_launch(void* const* d_in, const int* in_sizes, int n_in,
                              void* d_out, int out_size, void* d_ws,
                              size_t ws_size, hipStream_t stream) {
  const float* x  = (const float*)d_in[0];
  const float* Wq = (const float*)d_in[1];
  const float* bq = (const float*)d_in[2];
  const float* Wk = (const float*)d_in[3];
  const float* bk = (const float*)d_in[4];
  const float* Wv = (const float*)d_in[5];
  const float* bv = (const float*)d_in[6];
  const float* Wo = (const float*)d_in[7];
  const float* bo = (const float*)d_in[8];
  float* out = (float*)d_out;

  __bf16* xb   = (__bf16*)d_ws;
  __bf16* wall = xb + (size_t)Mrows * CDIM;
  __bf16* Qb   = wall + (size_t)4 * CDIM * CDIM;
  __bf16* Kb   = Qb + (size_t)Mrows * CDIM;
  __bf16* Vb   = Kb + (size_t)Mrows * CDIM;
  __bf16* AO   = Vb + (size_t)Mrows * CDIM;

  cast_inputs<<<2048, 256, 0, stream>>>(x, Wq, Wk, Wv, Wo, xb, wall);
  gemm_mfma<1><<<dim3(24, 64), 256, 0, stream>>>(xb, wall, bq, bk, bv, Qb, Kb,
                                                 Vb, nullptr);
  attn_mfma<<<dim3(Bn * NH, SEQ / 128), 256, 0, stream>>>(Qb, Kb, Vb, AO);
  gemm_mfma<0><<<dim3(8, 64), 256, 0, stream>>>(
      AO, wall + (size_t)3 * CDIM * CDIM, bo, nullptr, nullptr, nullptr,
      nullptr, nullptr, out);
}